// Round 1
// baseline (284.903 us; speedup 1.0000x reference)
//
#include <hip/hip_runtime.h>
#include <math.h>

#define B_ 4
#define N_ 1024
#define D_ 768
#define L_ 16
#define EPSF 1e-7f

typedef unsigned long long ull;

// ---------------- kernel 1: start/end head + sx/ex projections ----------------
// grid = B*N blocks (one x-row each), 256 threads.
// cols 0..31  -> se head (sigmoid, focal loss partial, predictions)
// cols 32..47 -> sx (w_sp rows 0..D-1)   [+ b_sp folded in]
// cols 48..63 -> ex (w_sp rows D..2D-1]
__global__ __launch_bounds__(256) void head_kernel(
    const float* __restrict__ x, const int* __restrict__ start, const int* __restrict__ end,
    const int* __restrict__ seqlen,
    const float* __restrict__ w_se, const float* __restrict__ b_se,
    const float* __restrict__ w_sp, const float* __restrict__ b_sp,
    float* __restrict__ out_start, float* __restrict__ out_end,
    float* __restrict__ sx_t, float* __restrict__ ex_t,
    int* __restrict__ spi, int* __restrict__ epi,
    float* __restrict__ part_se)
{
  __shared__ float xrow[D_];
  __shared__ float smf[4];
  int bid = blockIdx.x;
  int b = bid >> 10, n = bid & (N_ - 1);
  const float* xr = x + (size_t)bid * D_;
  for (int d = threadIdx.x; d < D_; d += 256) xrow[d] = xr[d];
  __syncthreads();

  int col  = threadIdx.x >> 2;   // 0..63
  int part = threadIdx.x & 3;    // 4 partial sums per col
  float sum = 0.f;
  if (col < 32) {
    const float* w = w_se + col;
    for (int d = part; d < D_; d += 4) sum += xrow[d] * w[d * 32];
  } else if (col < 48) {
    const float* w = w_sp + (col - 32);
    for (int d = part; d < D_; d += 4) sum += xrow[d] * w[d * 16];
  } else {
    const float* w = w_sp + (size_t)D_ * 16 + (col - 48);
    for (int d = part; d < D_; d += 4) sum += xrow[d] * w[d * 16];
  }
  sum += __shfl_xor(sum, 1, 64);
  sum += __shfl_xor(sum, 2, 64);

  float fl = 0.f;
  if (part == 0) {
    int mask = (n < seqlen[b]) ? 1 : 0;
    if (col < 32) {
      float z = sum + b_se[col];
      float p = 1.f / (1.f + expf(-z));
      int pred = (z > 0.f && mask) ? 1 : 0;
      int y = (col < L_) ? start[((b * L_ + col) << 10) | n]
                         : end[((b * L_ + (col - L_)) << 10) | n];
      float f = (y == 1) ? (-0.5f * (1.f - p) * (1.f - p) * logf(p + EPSF))
                         : (-0.5f * p * p * logf(1.f - p + EPSF));
      fl = mask ? f : 0.f;
      int o = ((b * L_ + (col & (L_ - 1))) << 10) | n;
      if (col < L_) { out_start[o] = (float)pred; spi[o] = pred; }
      else          { out_end[o]   = (float)pred; epi[o] = pred; }
    } else if (col < 48) {
      int l = col - 32;
      sx_t[((b * L_ + l) << 10) | n] = sum + b_sp[l];
    } else {
      int l = col - 48;
      ex_t[((b * L_ + l) << 10) | n] = sum;
    }
  }
  // block-reduce fl -> per-block partial (no global atomics)
  for (int o = 32; o > 0; o >>= 1) fl += __shfl_down(fl, o, 64);
  int wid = threadIdx.x >> 6, lane = threadIdx.x & 63;
  if (lane == 0) smf[wid] = fl;
  __syncthreads();
  if (threadIdx.x == 0) part_se[bid] = smf[0] + smf[1] + smf[2] + smf[3];
}

// ---------------- kernel 2: span sweep ----------------
// grid = B*L*N blocks (one (b,l,i) row each), 256 threads, 4 j's per thread.
__global__ __launch_bounds__(256) void span_kernel(
    const int* __restrict__ span, const int* __restrict__ val,
    const float* __restrict__ sx_t, const float* __restrict__ ex_t,
    const int* __restrict__ spi, const int* __restrict__ epi,
    float* __restrict__ out_span,
    float* __restrict__ part)   // [gridDim][8]: lsum,val,acc,tp,tn,fp
{
  int bid = blockIdx.x;            // (b*L + l)*N + i
  int i  = bid & (N_ - 1);
  int bl = bid >> 10;              // b*L + l
  size_t rowoff = (size_t)bid * N_;
  float s   = sx_t[(bl << 10) | i];
  int  sp_i = spi [(bl << 10) | i];

  int tid = threadIdx.x;
  int4   y4  = ((const int4*  )(span + rowoff))[tid];
  int4   v4  = ((const int4*  )(val  + rowoff))[tid];
  float4 e4  = ((const float4*)(ex_t + ((size_t)bl << 10)))[tid];
  int4   ep4 = ((const int4*  )(epi  + ((size_t)bl << 10)))[tid];

  int j0 = tid << 2;
  float lsum = 0.f;
  int c_val = 0, c_acc = 0, c_tp = 0, c_tn = 0, c_fp = 0;
  float4 o4;

#pragma unroll
  for (int k = 0; k < 4; ++k) {
    int j   = j0 + k;
    int y   = ((const int*)&y4)[k];
    int vv  = ((const int*)&v4)[k];
    float e = ((const float*)&e4)[k];
    int ep  = ((const int*)&ep4)[k];
    float z = s + e;
    float p = 1.f / (1.f + expf(-z));
    int pred = (z > 0.f && sp_i && ep && (j >= i)) ? 1 : 0;
    float f = (y == 1) ? (-0.5f * (1.f - p) * (1.f - p) * logf(p + EPSF))
                       : (-0.5f * p * p * logf(1.f - p + EPSF));
    lsum += f * (float)vv;
    c_val += vv;
    c_acc += (pred == y) ? vv : 0;
    c_tp  += (y == 1) & (pred == 1);
    c_tn  += (y == 1) & (pred == 0);
    c_fp  += (y == 0) & (pred == 1);
    ((float*)&o4)[k] = (float)pred;
  }
  ((float4*)(out_span + rowoff))[tid] = o4;

  for (int o = 32; o > 0; o >>= 1) {
    lsum  += __shfl_down(lsum,  o, 64);
    c_val += __shfl_down(c_val, o, 64);
    c_acc += __shfl_down(c_acc, o, 64);
    c_tp  += __shfl_down(c_tp,  o, 64);
    c_tn  += __shfl_down(c_tn,  o, 64);
    c_fp  += __shfl_down(c_fp,  o, 64);
  }
  __shared__ float smf[4];
  __shared__ int   smi[5][4];
  int wid = tid >> 6, lane = tid & 63;
  if (lane == 0) {
    smf[wid] = lsum;
    smi[0][wid] = c_val; smi[1][wid] = c_acc; smi[2][wid] = c_tp;
    smi[3][wid] = c_tn;  smi[4][wid] = c_fp;
  }
  __syncthreads();
  if (tid == 0) {
    float* p = part + (size_t)bid * 8;
    p[0] = smf[0] + smf[1] + smf[2] + smf[3];
    p[1] = (float)(smi[0][0] + smi[0][1] + smi[0][2] + smi[0][3]);
    p[2] = (float)(smi[1][0] + smi[1][1] + smi[1][2] + smi[1][3]);
    p[3] = (float)(smi[2][0] + smi[2][1] + smi[2][2] + smi[2][3]);
    p[4] = (float)(smi[3][0] + smi[3][1] + smi[3][2] + smi[3][3]);
    p[5] = (float)(smi[4][0] + smi[4][1] + smi[4][2] + smi[4][3]);
  }
}

// ---------------- kernel 3: reduce partials into double accumulators ----------------
// acc layout: [0] se_loss, [1] sp_loss, [2] val, [3] accsum, [4] tp, [5] tn, [6] fp
__global__ __launch_bounds__(256) void reduce_kernel(
    const float* __restrict__ part,     // [65536][8]
    const float* __restrict__ part_se,  // [4096]
    double* __restrict__ acc)
{
  int g = blockIdx.x;  // 0..63
  float s[6] = {0.f, 0.f, 0.f, 0.f, 0.f, 0.f};
  int base = g * 1024;
  for (int r = threadIdx.x; r < 1024; r += 256) {
    const float* p = part + (size_t)(base + r) * 8;
    s[0] += p[0]; s[1] += p[1]; s[2] += p[2];
    s[3] += p[3]; s[4] += p[4]; s[5] += p[5];
  }
  float se = 0.f;
  for (int r = threadIdx.x; r < 64; r += 256) se += part_se[g * 64 + r];

  for (int o = 32; o > 0; o >>= 1) {
    for (int q = 0; q < 6; ++q) s[q] += __shfl_down(s[q], o, 64);
    se += __shfl_down(se, o, 64);
  }
  __shared__ float smf[7][4];
  int wid = threadIdx.x >> 6, lane = threadIdx.x & 63;
  if (lane == 0) { for (int q = 0; q < 6; ++q) smf[q][wid] = s[q]; smf[6][wid] = se; }
  __syncthreads();
  if (threadIdx.x == 0) {
    atomicAdd(&acc[1], (double)(smf[0][0] + smf[0][1] + smf[0][2] + smf[0][3]));
    atomicAdd(&acc[2], (double)(smf[1][0] + smf[1][1] + smf[1][2] + smf[1][3]));
    atomicAdd(&acc[3], (double)(smf[2][0] + smf[2][1] + smf[2][2] + smf[2][3]));
    atomicAdd(&acc[4], (double)(smf[3][0] + smf[3][1] + smf[3][2] + smf[3][3]));
    atomicAdd(&acc[5], (double)(smf[4][0] + smf[4][1] + smf[4][2] + smf[4][3]));
    atomicAdd(&acc[6], (double)(smf[5][0] + smf[5][1] + smf[5][2] + smf[5][3]));
    atomicAdd(&acc[0], (double)(smf[6][0] + smf[6][1] + smf[6][2] + smf[6][3]));
  }
}

// ---------------- kernel 4: finalize scalars ----------------
__global__ void finalize_kernel(const double* __restrict__ acc,
                                const int* __restrict__ seqlen,
                                float* __restrict__ out_scal)
{
  if (threadIdx.x == 0) {
    double masks = 2.0 * L_ * (double)(seqlen[0] + seqlen[1] + seqlen[2] + seqlen[3]);
    double sel  = acc[0] / masks;
    double spl  = acc[1] / (acc[2] + 1e-7);
    double loss = 0.15 * sel + 0.7 * spl;
    out_scal[0] = (float)acc[4];  // tp
    out_scal[1] = (float)acc[5];  // tn
    out_scal[2] = (float)acc[6];  // fp
    out_scal[3] = (float)loss;    // loss
    out_scal[4] = (float)acc[3];  // accuracysum
    out_scal[5] = (float)acc[2];  // valsum
  }
}

extern "C" void kernel_launch(void* const* d_in, const int* in_sizes, int n_in,
                              void* d_out, int out_size, void* d_ws, size_t ws_size,
                              hipStream_t stream) {
  const float* x      = (const float*)d_in[0];
  const int*   start  = (const int*)  d_in[1];
  const int*   end    = (const int*)  d_in[2];
  const int*   span   = (const int*)  d_in[3];
  const int*   val    = (const int*)  d_in[4];
  const int*   seqlen = (const int*)  d_in[5];
  const float* w_se   = (const float*)d_in[6];
  const float* b_se   = (const float*)d_in[7];
  const float* w_sp   = (const float*)d_in[8];
  const float* b_sp   = (const float*)d_in[9];

  float* out = (float*)d_out;
  const size_t span_elems = (size_t)B_ * L_ * N_ * N_;   // 67,108,864
  const size_t se_elems   = (size_t)B_ * L_ * N_;        // 65,536
  float* out_span  = out;
  float* out_start = out + span_elems;
  float* out_end   = out_start + se_elems;
  float* out_scal  = out_end + se_elems;

  char* ws = (char*)d_ws;
  double* acc     = (double*)ws;                          // 8 doubles (64 B)
  float*  sx_t    = (float*)(ws + 64);                    // 262144 B
  float*  ex_t    = (float*)(ws + 64 + 262144);           // 262144 B
  int*    spi     = (int*)  (ws + 64 + 2 * 262144);       // 262144 B
  int*    epi     = (int*)  (ws + 64 + 3 * 262144);       // 262144 B
  float*  part    = (float*)(ws + 64 + 4 * 262144);       // 65536*8*4 = 2 MiB
  float*  part_se = (float*)(ws + 64 + 4 * 262144 + 2097152); // 4096*4 B

  hipMemsetAsync(acc, 0, 64, stream);

  head_kernel<<<B_ * N_, 256, 0, stream>>>(
      x, start, end, seqlen, w_se, b_se, w_sp, b_sp,
      out_start, out_end, sx_t, ex_t, spi, epi, part_se);

  span_kernel<<<B_ * L_ * N_, 256, 0, stream>>>(
      span, val, sx_t, ex_t, spi, epi, out_span, part);

  reduce_kernel<<<64, 256, 0, stream>>>(part, part_se, acc);

  finalize_kernel<<<1, 64, 0, stream>>>(acc, seqlen, out_scal);
}

// Round 2
// 278.890 us; speedup vs baseline: 1.0216x; 1.0216x over previous
//
#include <hip/hip_runtime.h>
#include <math.h>

#define B_ 4
#define N_ 1024
#define D_ 768
#define L_ 16
#define EPSF 1e-7f

typedef unsigned long long ull;

// ---------------- kernel 1: start/end head + sx/ex projections ----------------
// (unchanged from round 1 — keeps s/e dot-product rounding bit-identical so the
//  pred boundary (z>0) cannot flip vs the passing run)
__global__ __launch_bounds__(256) void head_kernel(
    const float* __restrict__ x, const int* __restrict__ start, const int* __restrict__ end,
    const int* __restrict__ seqlen,
    const float* __restrict__ w_se, const float* __restrict__ b_se,
    const float* __restrict__ w_sp, const float* __restrict__ b_sp,
    float* __restrict__ out_start, float* __restrict__ out_end,
    float* __restrict__ sx_t, float* __restrict__ ex_t,
    int* __restrict__ spi, int* __restrict__ epi,
    float* __restrict__ part_se)
{
  __shared__ float xrow[D_];
  __shared__ float smf[4];
  int bid = blockIdx.x;
  int b = bid >> 10, n = bid & (N_ - 1);
  const float* xr = x + (size_t)bid * D_;
  for (int d = threadIdx.x; d < D_; d += 256) xrow[d] = xr[d];
  __syncthreads();

  int col  = threadIdx.x >> 2;   // 0..63
  int part = threadIdx.x & 3;    // 4 partial sums per col
  float sum = 0.f;
  if (col < 32) {
    const float* w = w_se + col;
    for (int d = part; d < D_; d += 4) sum += xrow[d] * w[d * 32];
  } else if (col < 48) {
    const float* w = w_sp + (col - 32);
    for (int d = part; d < D_; d += 4) sum += xrow[d] * w[d * 16];
  } else {
    const float* w = w_sp + (size_t)D_ * 16 + (col - 48);
    for (int d = part; d < D_; d += 4) sum += xrow[d] * w[d * 16];
  }
  sum += __shfl_xor(sum, 1, 64);
  sum += __shfl_xor(sum, 2, 64);

  float fl = 0.f;
  if (part == 0) {
    int mask = (n < seqlen[b]) ? 1 : 0;
    if (col < 32) {
      float z = sum + b_se[col];
      float p = 1.f / (1.f + expf(-z));
      int pred = (z > 0.f && mask) ? 1 : 0;
      int y = (col < L_) ? start[((b * L_ + col) << 10) | n]
                         : end[((b * L_ + (col - L_)) << 10) | n];
      float f = (y == 1) ? (-0.5f * (1.f - p) * (1.f - p) * logf(p + EPSF))
                         : (-0.5f * p * p * logf(1.f - p + EPSF));
      fl = mask ? f : 0.f;
      int o = ((b * L_ + (col & (L_ - 1))) << 10) | n;
      if (col < L_) { out_start[o] = (float)pred; spi[o] = pred; }
      else          { out_end[o]   = (float)pred; epi[o] = pred; }
    } else if (col < 48) {
      int l = col - 32;
      sx_t[((b * L_ + l) << 10) | n] = sum + b_sp[l];
    } else {
      int l = col - 48;
      ex_t[((b * L_ + l) << 10) | n] = sum;
    }
  }
  for (int o = 32; o > 0; o >>= 1) fl += __shfl_down(fl, o, 64);
  int wid = threadIdx.x >> 6, lane = threadIdx.x & 63;
  if (lane == 0) smf[wid] = fl;
  __syncthreads();
  if (threadIdx.x == 0) part_se[bid] = smf[0] + smf[1] + smf[2] + smf[3];
}

// ---------------- kernel 2: span sweep (v2 — native trans, packed reduce) ----
// focal via softplus identity:
//   em = 2^(-z*log2e); p = rcp(1+em); U = log2(1+em)
//   y==1: f = 0.5*(1-p)^2 * (U*ln2)          [= -0.5 (1-p)^2 ln p]
//   y==0: f = 0.5*p^2 * (z + U*ln2)          [= -0.5 p^2 ln(1-p)]
// (eps dropped: relative effect ~1e-6 on the aggregated loss)
// pred logic unchanged: (z>0) && sp_i && ep && (j>=i), z = s+e exactly as v1.
__global__ __launch_bounds__(256) void span_kernel(
    const int* __restrict__ span, const int* __restrict__ val,
    const float* __restrict__ sx_t, const float* __restrict__ ex_t,
    const int* __restrict__ spi, const int* __restrict__ epi,
    float* __restrict__ out_span,
    float* __restrict__ part)   // [gridDim][8]: lsum,val,acc,tp,tn,fp
{
  const float L2E = 1.44269504f;
  const float LN2 = 0.69314718f;

  int bid = blockIdx.x;            // (b*L + l)*N + i
  int i  = bid & (N_ - 1);
  int bl = bid >> 10;              // b*L + l
  size_t rowoff = (size_t)bid * N_;
  float s   = sx_t[(bl << 10) | i];
  int  sp_i = spi [(bl << 10) | i] ? 1 : 0;

  int tid = threadIdx.x;
  int4   y4  = ((const int4*  )(span + rowoff))[tid];
  int4   v4  = ((const int4*  )(val  + rowoff))[tid];
  float4 e4  = ((const float4*)(ex_t + ((size_t)bl << 10)))[tid];
  int4   ep4 = ((const int4*  )(epi  + ((size_t)bl << 10)))[tid];

  int j0 = tid << 2;
  float lsum = 0.f;
  int a1 = 0;   // S_y | S_pred<<16
  int a2 = 0;   // S_(y&pred) | S_val<<16
  int a3 = 0;   // S_acc (val-gated pred==y)
  float4 o4;

#pragma unroll
  for (int k = 0; k < 4; ++k) {
    int j   = j0 + k;
    int y   = ((const int*)&y4)[k];
    int vv  = ((const int*)&v4)[k];
    float e = ((const float*)&e4)[k];
    int ep  = ((const int*)&ep4)[k];

    float z  = s + e;
    float em = __builtin_amdgcn_exp2f(z * -L2E);
    float dn = 1.f + em;
    float pr = __builtin_amdgcn_rcpf(dn);     // p
    float U  = __builtin_amdgcn_logf(dn);     // log2(1+em)
    float omp = em * pr;                      // 1-p
    bool  yp  = (y != 0);
    float tsel = yp ? omp : pr;
    float Lv   = fmaf(U, LN2, yp ? 0.f : z);  // -ln(p) or -ln(1-p)
    float fv   = tsel * tsel * Lv;            // 2*focal (0.5 folded at end)
    lsum += vv ? fv : 0.f;

    int gate = (ep & sp_i) & ((j >= i) ? 1 : 0);
    int predi = (z > 0.f) ? gate : 0;
    ((float*)&o4)[k] = (float)predi;

    a1 += y + (predi << 16);
    a2 += (y & predi) + (vv << 16);
    a3 += (predi == y) ? vv : 0;
  }
  ((float4*)(out_span + rowoff))[tid] = o4;

  for (int o = 32; o > 0; o >>= 1) {
    lsum += __shfl_down(lsum, o, 64);
    a1   += __shfl_down(a1,   o, 64);
    a2   += __shfl_down(a2,   o, 64);
    a3   += __shfl_down(a3,   o, 64);
  }
  __shared__ float smf[4];
  __shared__ int   smi[3][4];
  int wid = tid >> 6, lane = tid & 63;
  if (lane == 0) { smf[wid] = lsum; smi[0][wid] = a1; smi[1][wid] = a2; smi[2][wid] = a3; }
  __syncthreads();
  if (tid == 0) {
    float ls = smf[0] + smf[1] + smf[2] + smf[3];
    int r1 = smi[0][0] + smi[0][1] + smi[0][2] + smi[0][3];
    int r2 = smi[1][0] + smi[1][1] + smi[1][2] + smi[1][3];
    int r3 = smi[2][0] + smi[2][1] + smi[2][2] + smi[2][3];
    int S_y = r1 & 0xffff, S_p = r1 >> 16;
    int S_yp = r2 & 0xffff, S_v = r2 >> 16;
    float* p = part + (size_t)bid * 8;
    p[0] = 0.5f * ls;               // focal loss partial
    p[1] = (float)S_v;              // val sum
    p[2] = (float)r3;               // accuracy sum
    p[3] = (float)S_yp;             // tp
    p[4] = (float)(S_y - S_yp);     // tn
    p[5] = (float)(S_p - S_yp);     // fp
  }
}

// ---------------- kernel 3: reduce partials into double accumulators ----------------
// acc layout: [0] se_loss, [1] sp_loss, [2] val, [3] accsum, [4] tp, [5] tn, [6] fp
__global__ __launch_bounds__(256) void reduce_kernel(
    const float* __restrict__ part,     // [65536][8]
    const float* __restrict__ part_se,  // [4096]
    double* __restrict__ acc)
{
  int g = blockIdx.x;  // 0..63
  float s[6] = {0.f, 0.f, 0.f, 0.f, 0.f, 0.f};
  int base = g * 1024;
  for (int r = threadIdx.x; r < 1024; r += 256) {
    const float* p = part + (size_t)(base + r) * 8;
    s[0] += p[0]; s[1] += p[1]; s[2] += p[2];
    s[3] += p[3]; s[4] += p[4]; s[5] += p[5];
  }
  float se = 0.f;
  for (int r = threadIdx.x; r < 64; r += 256) se += part_se[g * 64 + r];

  for (int o = 32; o > 0; o >>= 1) {
    for (int q = 0; q < 6; ++q) s[q] += __shfl_down(s[q], o, 64);
    se += __shfl_down(se, o, 64);
  }
  __shared__ float smf[7][4];
  int wid = threadIdx.x >> 6, lane = threadIdx.x & 63;
  if (lane == 0) { for (int q = 0; q < 6; ++q) smf[q][wid] = s[q]; smf[6][wid] = se; }
  __syncthreads();
  if (threadIdx.x == 0) {
    atomicAdd(&acc[1], (double)(smf[0][0] + smf[0][1] + smf[0][2] + smf[0][3]));
    atomicAdd(&acc[2], (double)(smf[1][0] + smf[1][1] + smf[1][2] + smf[1][3]));
    atomicAdd(&acc[3], (double)(smf[2][0] + smf[2][1] + smf[2][2] + smf[2][3]));
    atomicAdd(&acc[4], (double)(smf[3][0] + smf[3][1] + smf[3][2] + smf[3][3]));
    atomicAdd(&acc[5], (double)(smf[4][0] + smf[4][1] + smf[4][2] + smf[4][3]));
    atomicAdd(&acc[6], (double)(smf[5][0] + smf[5][1] + smf[5][2] + smf[5][3]));
    atomicAdd(&acc[0], (double)(smf[6][0] + smf[6][1] + smf[6][2] + smf[6][3]));
  }
}

// ---------------- kernel 4: finalize scalars ----------------
__global__ void finalize_kernel(const double* __restrict__ acc,
                                const int* __restrict__ seqlen,
                                float* __restrict__ out_scal)
{
  if (threadIdx.x == 0) {
    double masks = 2.0 * L_ * (double)(seqlen[0] + seqlen[1] + seqlen[2] + seqlen[3]);
    double sel  = acc[0] / masks;
    double spl  = acc[1] / (acc[2] + 1e-7);
    double loss = 0.15 * sel + 0.7 * spl;
    out_scal[0] = (float)acc[4];  // tp
    out_scal[1] = (float)acc[5];  // tn
    out_scal[2] = (float)acc[6];  // fp
    out_scal[3] = (float)loss;    // loss
    out_scal[4] = (float)acc[3];  // accuracysum
    out_scal[5] = (float)acc[2];  // valsum
  }
}

extern "C" void kernel_launch(void* const* d_in, const int* in_sizes, int n_in,
                              void* d_out, int out_size, void* d_ws, size_t ws_size,
                              hipStream_t stream) {
  const float* x      = (const float*)d_in[0];
  const int*   start  = (const int*)  d_in[1];
  const int*   end    = (const int*)  d_in[2];
  const int*   span   = (const int*)  d_in[3];
  const int*   val    = (const int*)  d_in[4];
  const int*   seqlen = (const int*)  d_in[5];
  const float* w_se   = (const float*)d_in[6];
  const float* b_se   = (const float*)d_in[7];
  const float* w_sp   = (const float*)d_in[8];
  const float* b_sp   = (const float*)d_in[9];

  float* out = (float*)d_out;
  const size_t span_elems = (size_t)B_ * L_ * N_ * N_;   // 67,108,864
  const size_t se_elems   = (size_t)B_ * L_ * N_;        // 65,536
  float* out_span  = out;
  float* out_start = out + span_elems;
  float* out_end   = out_start + se_elems;
  float* out_scal  = out_end + se_elems;

  char* ws = (char*)d_ws;
  double* acc     = (double*)ws;                          // 8 doubles (64 B)
  float*  sx_t    = (float*)(ws + 64);                    // 262144 B
  float*  ex_t    = (float*)(ws + 64 + 262144);           // 262144 B
  int*    spi     = (int*)  (ws + 64 + 2 * 262144);       // 262144 B
  int*    epi     = (int*)  (ws + 64 + 3 * 262144);       // 262144 B
  float*  part    = (float*)(ws + 64 + 4 * 262144);       // 65536*8*4 = 2 MiB
  float*  part_se = (float*)(ws + 64 + 4 * 262144 + 2097152); // 4096*4 B

  hipMemsetAsync(acc, 0, 64, stream);

  head_kernel<<<B_ * N_, 256, 0, stream>>>(
      x, start, end, seqlen, w_se, b_se, w_sp, b_sp,
      out_start, out_end, sx_t, ex_t, spi, epi, part_se);

  span_kernel<<<B_ * L_ * N_, 256, 0, stream>>>(
      span, val, sx_t, ex_t, spi, epi, out_span, part);

  reduce_kernel<<<64, 256, 0, stream>>>(part, part_se, acc);

  finalize_kernel<<<1, 64, 0, stream>>>(acc, seqlen, out_scal);
}

// Round 3
// 251.016 us; speedup vs baseline: 1.1350x; 1.1110x over previous
//
#include <hip/hip_runtime.h>
#include <math.h>

#define B_ 4
#define N_ 1024
#define D_ 768
#define L_ 16
#define EPSF 1e-7f

typedef unsigned long long ull;

// ---------------- kernel 1: start/end head + sx/ex projections (v3) ----------
// grid = B*N/8 = 512 blocks; each block computes 8 consecutive x-rows.
// Per-row accumulation order is BIT-IDENTICAL to v1/v2:
//   (col,part) partial over d = part, part+4, ..., then shfl_xor 1,2 pairing.
// Weights are loaded once per 8 rows (L2 weight traffic /8).
__global__ __launch_bounds__(256) void head_kernel(
    const float* __restrict__ x, const int* __restrict__ start, const int* __restrict__ end,
    const int* __restrict__ seqlen,
    const float* __restrict__ w_se, const float* __restrict__ b_se,
    const float* __restrict__ w_sp, const float* __restrict__ b_sp,
    float* __restrict__ out_start, float* __restrict__ out_end,
    float* __restrict__ sx_t, float* __restrict__ ex_t,
    int* __restrict__ spi, int* __restrict__ epi,
    float* __restrict__ part_se)
{
  __shared__ float xt[8][D_];   // 24 KB
  __shared__ float smf[4];
  int bid = blockIdx.x;
  int b  = bid >> 7;            // 4 batches * 128 chunks
  int n0 = (bid & 127) << 3;
  int tid = threadIdx.x;

#pragma unroll
  for (int r = 0; r < 8; ++r)
    for (int d = tid; d < D_; d += 256)
      xt[r][d] = x[((size_t)(b * N_ + n0 + r)) * D_ + d];
  __syncthreads();

  int col  = tid >> 2;   // 0..63
  int part = tid & 3;
  float acc[8] = {0.f,0.f,0.f,0.f,0.f,0.f,0.f,0.f};

  if (col < 32) {
    const float* w = w_se + col;
    for (int d = part; d < D_; d += 4) {
      float wv = w[d * 32];
#pragma unroll
      for (int r = 0; r < 8; ++r) acc[r] += xt[r][d] * wv;
    }
  } else if (col < 48) {
    const float* w = w_sp + (col - 32);
    for (int d = part; d < D_; d += 4) {
      float wv = w[d * 16];
#pragma unroll
      for (int r = 0; r < 8; ++r) acc[r] += xt[r][d] * wv;
    }
  } else {
    const float* w = w_sp + (size_t)D_ * 16 + (col - 48);
    for (int d = part; d < D_; d += 4) {
      float wv = w[d * 16];
#pragma unroll
      for (int r = 0; r < 8; ++r) acc[r] += xt[r][d] * wv;
    }
  }
#pragma unroll
  for (int r = 0; r < 8; ++r) {
    acc[r] += __shfl_xor(acc[r], 1, 64);
    acc[r] += __shfl_xor(acc[r], 2, 64);
  }

  float fl = 0.f;
  if (part == 0) {
    int sl = seqlen[b];
    if (col < 32) {
      float bse = b_se[col];
#pragma unroll
      for (int r = 0; r < 8; ++r) {
        int n = n0 + r;
        int mask = (n < sl) ? 1 : 0;
        float z = acc[r] + bse;
        float p = 1.f / (1.f + expf(-z));
        int pred = (z > 0.f && mask) ? 1 : 0;
        int y = (col < L_) ? start[((b * L_ + col) << 10) | n]
                           : end[((b * L_ + (col - L_)) << 10) | n];
        float f = (y == 1) ? (-0.5f * (1.f - p) * (1.f - p) * logf(p + EPSF))
                           : (-0.5f * p * p * logf(1.f - p + EPSF));
        fl += mask ? f : 0.f;
        int o = ((b * L_ + (col & (L_ - 1))) << 10) | n;
        if (col < L_) { out_start[o] = (float)pred; spi[o] = pred; }
        else          { out_end[o]   = (float)pred; epi[o] = pred; }
      }
    } else if (col < 48) {
      int l = col - 32;
      float bb = b_sp[l];
#pragma unroll
      for (int r = 0; r < 8; ++r)
        sx_t[((b * L_ + l) << 10) | (n0 + r)] = acc[r] + bb;
    } else {
      int l = col - 48;
#pragma unroll
      for (int r = 0; r < 8; ++r)
        ex_t[((b * L_ + l) << 10) | (n0 + r)] = acc[r];
    }
  }
  for (int o = 32; o > 0; o >>= 1) fl += __shfl_down(fl, o, 64);
  int wid = tid >> 6, lane = tid & 63;
  if (lane == 0) smf[wid] = fl;
  __syncthreads();
  if (tid == 0) part_se[bid] = smf[0] + smf[1] + smf[2] + smf[3];
}

// ---------------- kernel 2: span sweep (v3 — 8 rows/block) -------------------
// grid = B*L*N/8 = 8192 blocks. One reduction per 8 rows; ex/epi loaded once.
__global__ __launch_bounds__(256) void span_kernel(
    const int* __restrict__ span, const int* __restrict__ val,
    const float* __restrict__ sx_t, const float* __restrict__ ex_t,
    const int* __restrict__ spi, const int* __restrict__ epi,
    float* __restrict__ out_span,
    float* __restrict__ part)
{
  const float L2E = 1.44269504f;
  const float LN2 = 0.69314718f;

  int bid = blockIdx.x;
  int bl  = bid >> 7;            // b*L + l
  int i0  = (bid & 127) << 3;
  int tid = threadIdx.x;

  float4 e4  = ((const float4*)(ex_t + ((size_t)bl << 10)))[tid];
  int4   ep4 = ((const int4*  )(epi  + ((size_t)bl << 10)))[tid];

  float s_r[8]; int sp_r[8];
#pragma unroll
  for (int r = 0; r < 8; ++r) {
    s_r[r]  = sx_t[(bl << 10) | (i0 + r)];
    sp_r[r] = spi [(bl << 10) | (i0 + r)] ? 1 : 0;
  }

  int j0 = tid << 2;
  float lsum = 0.f;
  int a1 = 0, a2 = 0, a3 = 0;

#pragma unroll
  for (int r = 0; r < 8; ++r) {
    int i = i0 + r;
    size_t rowoff = ((size_t)((bl << 10) | i)) << 10;
    int4 y4 = ((const int4*)(span + rowoff))[tid];
    int4 v4 = ((const int4*)(val  + rowoff))[tid];
    float s = s_r[r];
    int sp_i = sp_r[r];
    float4 o4;
#pragma unroll
    for (int k = 0; k < 4; ++k) {
      int j   = j0 + k;
      int y   = ((const int*)&y4)[k];
      int vv  = ((const int*)&v4)[k];
      float e = ((const float*)&e4)[k];
      int ep  = ((const int*)&ep4)[k];

      float z  = s + e;
      float em = __builtin_amdgcn_exp2f(z * -L2E);
      float dn = 1.f + em;
      float pr = __builtin_amdgcn_rcpf(dn);
      float U  = __builtin_amdgcn_logf(dn);
      float omp = em * pr;
      bool  yp  = (y != 0);
      float tsel = yp ? omp : pr;
      float Lv   = fmaf(U, LN2, yp ? 0.f : z);
      float fv   = tsel * tsel * Lv;
      lsum += vv ? fv : 0.f;

      int gate = (ep & sp_i) & ((j >= i) ? 1 : 0);
      int predi = (z > 0.f) ? gate : 0;
      ((float*)&o4)[k] = (float)predi;

      a1 += y + (predi << 16);
      a2 += (y & predi) + (vv << 16);
      a3 += (predi == y) ? vv : 0;
    }
    ((float4*)(out_span + rowoff))[tid] = o4;
  }

  for (int o = 32; o > 0; o >>= 1) {
    lsum += __shfl_down(lsum, o, 64);
    a1   += __shfl_down(a1,   o, 64);
    a2   += __shfl_down(a2,   o, 64);
    a3   += __shfl_down(a3,   o, 64);
  }
  __shared__ float smf[4];
  __shared__ int   smi[3][4];
  int wid = tid >> 6, lane = tid & 63;
  if (lane == 0) { smf[wid] = lsum; smi[0][wid] = a1; smi[1][wid] = a2; smi[2][wid] = a3; }
  __syncthreads();
  if (tid == 0) {
    float ls = smf[0] + smf[1] + smf[2] + smf[3];
    int r1 = smi[0][0] + smi[0][1] + smi[0][2] + smi[0][3];
    int r2 = smi[1][0] + smi[1][1] + smi[1][2] + smi[1][3];
    int r3 = smi[2][0] + smi[2][1] + smi[2][2] + smi[2][3];
    int S_y = r1 & 0xffff, S_p = r1 >> 16;
    int S_yp = r2 & 0xffff, S_v = r2 >> 16;
    float* p = part + (size_t)bid * 8;
    p[0] = 0.5f * ls;
    p[1] = (float)S_v;
    p[2] = (float)r3;
    p[3] = (float)S_yp;
    p[4] = (float)(S_y - S_yp);
    p[5] = (float)(S_p - S_yp);
  }
}

// ---------------- kernel 3: reduce partials --------------------------------
// part: [8192][8], part_se: [512]
// acc layout: [0] se_loss, [1] sp_loss, [2] val, [3] accsum, [4] tp, [5] tn, [6] fp
__global__ __launch_bounds__(256) void reduce_kernel(
    const float* __restrict__ part,
    const float* __restrict__ part_se,
    double* __restrict__ acc)
{
  int g = blockIdx.x;  // 0..63
  float s[6] = {0.f, 0.f, 0.f, 0.f, 0.f, 0.f};
  for (int r = threadIdx.x; r < 128; r += 256) {
    const float* p = part + (size_t)(g * 128 + r) * 8;
    s[0] += p[0]; s[1] += p[1]; s[2] += p[2];
    s[3] += p[3]; s[4] += p[4]; s[5] += p[5];
  }
  float se = (threadIdx.x < 8) ? part_se[g * 8 + threadIdx.x] : 0.f;

  for (int o = 32; o > 0; o >>= 1) {
    for (int q = 0; q < 6; ++q) s[q] += __shfl_down(s[q], o, 64);
    se += __shfl_down(se, o, 64);
  }
  __shared__ float smf[7][4];
  int wid = threadIdx.x >> 6, lane = threadIdx.x & 63;
  if (lane == 0) { for (int q = 0; q < 6; ++q) smf[q][wid] = s[q]; smf[6][wid] = se; }
  __syncthreads();
  if (threadIdx.x == 0) {
    atomicAdd(&acc[1], (double)(smf[0][0] + smf[0][1] + smf[0][2] + smf[0][3]));
    atomicAdd(&acc[2], (double)(smf[1][0] + smf[1][1] + smf[1][2] + smf[1][3]));
    atomicAdd(&acc[3], (double)(smf[2][0] + smf[2][1] + smf[2][2] + smf[2][3]));
    atomicAdd(&acc[4], (double)(smf[3][0] + smf[3][1] + smf[3][2] + smf[3][3]));
    atomicAdd(&acc[5], (double)(smf[4][0] + smf[4][1] + smf[4][2] + smf[4][3]));
    atomicAdd(&acc[6], (double)(smf[5][0] + smf[5][1] + smf[5][2] + smf[5][3]));
    atomicAdd(&acc[0], (double)(smf[6][0] + smf[6][1] + smf[6][2] + smf[6][3]));
  }
}

// ---------------- kernel 4: finalize scalars ----------------
__global__ void finalize_kernel(const double* __restrict__ acc,
                                const int* __restrict__ seqlen,
                                float* __restrict__ out_scal)
{
  if (threadIdx.x == 0) {
    double masks = 2.0 * L_ * (double)(seqlen[0] + seqlen[1] + seqlen[2] + seqlen[3]);
    double sel  = acc[0] / masks;
    double spl  = acc[1] / (acc[2] + 1e-7);
    double loss = 0.15 * sel + 0.7 * spl;
    out_scal[0] = (float)acc[4];  // tp
    out_scal[1] = (float)acc[5];  // tn
    out_scal[2] = (float)acc[6];  // fp
    out_scal[3] = (float)loss;    // loss
    out_scal[4] = (float)acc[3];  // accuracysum
    out_scal[5] = (float)acc[2];  // valsum
  }
}

extern "C" void kernel_launch(void* const* d_in, const int* in_sizes, int n_in,
                              void* d_out, int out_size, void* d_ws, size_t ws_size,
                              hipStream_t stream) {
  const float* x      = (const float*)d_in[0];
  const int*   start  = (const int*)  d_in[1];
  const int*   end    = (const int*)  d_in[2];
  const int*   span   = (const int*)  d_in[3];
  const int*   val    = (const int*)  d_in[4];
  const int*   seqlen = (const int*)  d_in[5];
  const float* w_se   = (const float*)d_in[6];
  const float* b_se   = (const float*)d_in[7];
  const float* w_sp   = (const float*)d_in[8];
  const float* b_sp   = (const float*)d_in[9];

  float* out = (float*)d_out;
  const size_t span_elems = (size_t)B_ * L_ * N_ * N_;   // 67,108,864
  const size_t se_elems   = (size_t)B_ * L_ * N_;        // 65,536
  float* out_span  = out;
  float* out_start = out + span_elems;
  float* out_end   = out_start + se_elems;
  float* out_scal  = out_end + se_elems;

  char* ws = (char*)d_ws;
  double* acc     = (double*)ws;                          // 8 doubles (64 B)
  float*  sx_t    = (float*)(ws + 64);                    // 262144 B
  float*  ex_t    = (float*)(ws + 64 + 262144);           // 262144 B
  int*    spi     = (int*)  (ws + 64 + 2 * 262144);       // 262144 B
  int*    epi     = (int*)  (ws + 64 + 3 * 262144);       // 262144 B
  float*  part    = (float*)(ws + 64 + 4 * 262144);       // 8192*8*4 = 256 KiB
  float*  part_se = (float*)(ws + 64 + 4 * 262144 + 262144); // 512*4 B

  hipMemsetAsync(acc, 0, 64, stream);

  head_kernel<<<512, 256, 0, stream>>>(
      x, start, end, seqlen, w_se, b_se, w_sp, b_sp,
      out_start, out_end, sx_t, ex_t, spi, epi, part_se);

  span_kernel<<<8192, 256, 0, stream>>>(
      span, val, sx_t, ex_t, spi, epi, out_span, part);

  reduce_kernel<<<64, 256, 0, stream>>>(part, part_se, acc);

  finalize_kernel<<<1, 64, 0, stream>>>(acc, seqlen, out_scal);
}

// Round 5
// 203.874 us; speedup vs baseline: 1.3974x; 1.2312x over previous
//
#include <hip/hip_runtime.h>
#include <math.h>

#define B_ 4
#define N_ 1024
#define D_ 768
#define L_ 16
#define DC_ 192
#define EPSF 1e-7f

typedef unsigned long long ull;
typedef float vf4 __attribute__((ext_vector_type(4)));   // native vec for NT store

// ---------------- kernel 1: start/end head + sx/ex projections (v4) ----------
// LDS-staged weights (coalesced float4 global loads, broadcast LDS reads).
// Per-thread accumulation sequence d = part, part+4, ... ascending is
// BIT-IDENTICAL to v1-v3 (chunks are contiguous in d), so z / sx / ex and all
// pred boundaries are unchanged.
__global__ __launch_bounds__(256) void head_kernel(
    const float* __restrict__ x, const int* __restrict__ start, const int* __restrict__ end,
    const int* __restrict__ seqlen,
    const float* __restrict__ w_se, const float* __restrict__ b_se,
    const float* __restrict__ w_sp, const float* __restrict__ b_sp,
    float* __restrict__ out_start, float* __restrict__ out_end,
    float* __restrict__ sx_t, float* __restrict__ ex_t,
    int* __restrict__ spi, int* __restrict__ epi,
    float* __restrict__ part_se)
{
  __shared__ float xt[8][D_];     // 24 KB
  __shared__ float xw[DC_][64];   // 48 KB: cols 0-31 w_se, 32-47 w_sp[:D], 48-63 w_sp[D:]
  __shared__ float smf[4];
  int bid = blockIdx.x;
  int b  = bid >> 7;
  int n0 = (bid & 127) << 3;
  int tid = threadIdx.x;

  {
    float4* xt4 = (float4*)xt;
    const float4* x4 = (const float4*)(x + (size_t)(b * N_ + n0) * D_);
    for (int idx = tid; idx < 8 * D_ / 4; idx += 256) xt4[idx] = x4[idx];
  }

  int col  = tid >> 2;   // 0..63
  int part = tid & 3;
  float acc[8] = {0.f,0.f,0.f,0.f,0.f,0.f,0.f,0.f};

  for (int c = 0; c < D_ / DC_; ++c) {   // 4 chunks of 192 dims
    int d0 = c * DC_;
    __syncthreads();   // protects xw overwrite (and xt on first iter)
    for (int idx = tid; idx < DC_ * 8; idx += 256) {
      int dd = idx >> 3, cc = idx & 7;
      ((float4*)&xw[dd][0])[cc] = ((const float4*)(w_se + (size_t)(d0 + dd) * 32))[cc];
    }
    for (int idx = tid; idx < DC_ * 4; idx += 256) {
      int dd = idx >> 2, cc = idx & 3;
      ((float4*)&xw[dd][32])[cc] = ((const float4*)(w_sp + (size_t)(d0 + dd) * 16))[cc];
      ((float4*)&xw[dd][48])[cc] = ((const float4*)(w_sp + (size_t)(D_ + d0 + dd) * 16))[cc];
    }
    __syncthreads();
    for (int d = part; d < DC_; d += 4) {
      float wv = xw[d][col];
#pragma unroll
      for (int r = 0; r < 8; ++r) acc[r] += xt[r][d0 + d] * wv;
    }
  }

#pragma unroll
  for (int r = 0; r < 8; ++r) {
    acc[r] += __shfl_xor(acc[r], 1, 64);
    acc[r] += __shfl_xor(acc[r], 2, 64);
  }

  float fl = 0.f;
  if (part == 0) {
    int sl = seqlen[b];
    if (col < 32) {
      float bse = b_se[col];
#pragma unroll
      for (int r = 0; r < 8; ++r) {
        int n = n0 + r;
        int mask = (n < sl) ? 1 : 0;
        float z = acc[r] + bse;
        float p = 1.f / (1.f + expf(-z));
        int pred = (z > 0.f && mask) ? 1 : 0;
        int y = (col < L_) ? start[((b * L_ + col) << 10) | n]
                           : end[((b * L_ + (col - L_)) << 10) | n];
        float f = (y == 1) ? (-0.5f * (1.f - p) * (1.f - p) * logf(p + EPSF))
                           : (-0.5f * p * p * logf(1.f - p + EPSF));
        fl += mask ? f : 0.f;
        int o = ((b * L_ + (col & (L_ - 1))) << 10) | n;
        if (col < L_) { out_start[o] = (float)pred; spi[o] = pred; }
        else          { out_end[o]   = (float)pred; epi[o] = pred; }
      }
    } else if (col < 48) {
      int l = col - 32;
      float bb = b_sp[l];
#pragma unroll
      for (int r = 0; r < 8; ++r)
        sx_t[((b * L_ + l) << 10) | (n0 + r)] = acc[r] + bb;
    } else {
      int l = col - 48;
#pragma unroll
      for (int r = 0; r < 8; ++r)
        ex_t[((b * L_ + l) << 10) | (n0 + r)] = acc[r];
    }
  }
  for (int o = 32; o > 0; o >>= 1) fl += __shfl_down(fl, o, 64);
  int wid = tid >> 6, lane = tid & 63;
  if (lane == 0) smf[wid] = fl;
  __syncthreads();
  if (tid == 0) part_se[bid] = smf[0] + smf[1] + smf[2] + smf[3];
}

// ---------------- kernel 2: span sweep (v4 — depth-2 pipeline + NT stores) ---
// Same element math and accumulation order as v3; only load scheduling and
// store cache-policy changed.
__global__ __launch_bounds__(256) void span_kernel(
    const int* __restrict__ span, const int* __restrict__ val,
    const float* __restrict__ sx_t, const float* __restrict__ ex_t,
    const int* __restrict__ spi, const int* __restrict__ epi,
    float* __restrict__ out_span,
    float* __restrict__ part)
{
  const float L2E = 1.44269504f;
  const float LN2 = 0.69314718f;

  int bid = blockIdx.x;
  int bl  = bid >> 7;            // b*L + l
  int i0  = (bid & 127) << 3;
  int tid = threadIdx.x;

  float4 e4  = ((const float4*)(ex_t + ((size_t)bl << 10)))[tid];
  int4   ep4 = ((const int4*  )(epi  + ((size_t)bl << 10)))[tid];

  float s_r[8]; int sp_r[8];
#pragma unroll
  for (int r = 0; r < 8; ++r) {
    s_r[r]  = sx_t[(bl << 10) | (i0 + r)];
    sp_r[r] = spi [(bl << 10) | (i0 + r)] ? 1 : 0;
  }

  size_t base = (((size_t)bl << 10) | (size_t)i0) << 10;  // element offset of row i0
  const int4* yrow = (const int4*)(span + base);
  const int4* vrow = (const int4*)(val  + base);
  vf4*        orow = (vf4*)(out_span + base);

  int j0 = tid << 2;
  float lsum = 0.f;
  int a1 = 0, a2 = 0, a3 = 0;

  int4 ya = yrow[tid];
  int4 va = vrow[tid];

#pragma unroll
  for (int r = 0; r < 8; ++r) {
    int4 yn, vn;
    if (r < 7) {
      yn = yrow[(r + 1) * 256 + tid];
      vn = vrow[(r + 1) * 256 + tid];
    }
    int i = i0 + r;
    float s = s_r[r];
    int sp_i = sp_r[r];
    vf4 o4;
#pragma unroll
    for (int k = 0; k < 4; ++k) {
      int j   = j0 + k;
      int y   = ((const int*)&ya)[k];
      int vv  = ((const int*)&va)[k];
      float e = ((const float*)&e4)[k];
      int ep  = ((const int*)&ep4)[k];

      float z  = s + e;
      float em = __builtin_amdgcn_exp2f(z * -L2E);
      float dn = 1.f + em;
      float pr = __builtin_amdgcn_rcpf(dn);
      float U  = __builtin_amdgcn_logf(dn);
      float omp = em * pr;
      bool  yp  = (y != 0);
      float tsel = yp ? omp : pr;
      float Lv   = fmaf(U, LN2, yp ? 0.f : z);
      float fv   = tsel * tsel * Lv;
      lsum += vv ? fv : 0.f;

      int gate = (ep & sp_i) & ((j >= i) ? 1 : 0);
      int predi = (z > 0.f) ? gate : 0;
      o4[k] = (float)predi;

      a1 += y + (predi << 16);
      a2 += (y & predi) + (vv << 16);
      a3 += (predi == y) ? vv : 0;
    }
    __builtin_nontemporal_store(o4, orow + r * 256 + tid);
    ya = yn; va = vn;
  }

  for (int o = 32; o > 0; o >>= 1) {
    lsum += __shfl_down(lsum, o, 64);
    a1   += __shfl_down(a1,   o, 64);
    a2   += __shfl_down(a2,   o, 64);
    a3   += __shfl_down(a3,   o, 64);
  }
  __shared__ float smf[4];
  __shared__ int   smi[3][4];
  int wid = tid >> 6, lane = tid & 63;
  if (lane == 0) { smf[wid] = lsum; smi[0][wid] = a1; smi[1][wid] = a2; smi[2][wid] = a3; }
  __syncthreads();
  if (tid == 0) {
    float ls = smf[0] + smf[1] + smf[2] + smf[3];
    int r1 = smi[0][0] + smi[0][1] + smi[0][2] + smi[0][3];
    int r2 = smi[1][0] + smi[1][1] + smi[1][2] + smi[1][3];
    int r3 = smi[2][0] + smi[2][1] + smi[2][2] + smi[2][3];
    int S_y = r1 & 0xffff, S_p = r1 >> 16;
    int S_yp = r2 & 0xffff, S_v = r2 >> 16;
    float* p = part + (size_t)bid * 8;
    p[0] = 0.5f * ls;
    p[1] = (float)S_v;
    p[2] = (float)r3;
    p[3] = (float)S_yp;
    p[4] = (float)(S_y - S_yp);
    p[5] = (float)(S_p - S_yp);
  }
}

// ---------------- kernel 3: reduce partials --------------------------------
// part: [8192][8], part_se: [512]
// acc layout: [0] se_loss, [1] sp_loss, [2] val, [3] accsum, [4] tp, [5] tn, [6] fp
__global__ __launch_bounds__(256) void reduce_kernel(
    const float* __restrict__ part,
    const float* __restrict__ part_se,
    double* __restrict__ acc)
{
  int g = blockIdx.x;  // 0..63
  float s[6] = {0.f, 0.f, 0.f, 0.f, 0.f, 0.f};
  for (int r = threadIdx.x; r < 128; r += 256) {
    const float* p = part + (size_t)(g * 128 + r) * 8;
    s[0] += p[0]; s[1] += p[1]; s[2] += p[2];
    s[3] += p[3]; s[4] += p[4]; s[5] += p[5];
  }
  float se = (threadIdx.x < 8) ? part_se[g * 8 + threadIdx.x] : 0.f;

  for (int o = 32; o > 0; o >>= 1) {
    for (int q = 0; q < 6; ++q) s[q] += __shfl_down(s[q], o, 64);
    se += __shfl_down(se, o, 64);
  }
  __shared__ float smf[7][4];
  int wid = threadIdx.x >> 6, lane = threadIdx.x & 63;
  if (lane == 0) { for (int q = 0; q < 6; ++q) smf[q][wid] = s[q]; smf[6][wid] = se; }
  __syncthreads();
  if (threadIdx.x == 0) {
    atomicAdd(&acc[1], (double)(smf[0][0] + smf[0][1] + smf[0][2] + smf[0][3]));
    atomicAdd(&acc[2], (double)(smf[1][0] + smf[1][1] + smf[1][2] + smf[1][3]));
    atomicAdd(&acc[3], (double)(smf[2][0] + smf[2][1] + smf[2][2] + smf[2][3]));
    atomicAdd(&acc[4], (double)(smf[3][0] + smf[3][1] + smf[3][2] + smf[3][3]));
    atomicAdd(&acc[5], (double)(smf[4][0] + smf[4][1] + smf[4][2] + smf[4][3]));
    atomicAdd(&acc[6], (double)(smf[5][0] + smf[5][1] + smf[5][2] + smf[5][3]));
    atomicAdd(&acc[0], (double)(smf[6][0] + smf[6][1] + smf[6][2] + smf[6][3]));
  }
}

// ---------------- kernel 4: finalize scalars ----------------
__global__ void finalize_kernel(const double* __restrict__ acc,
                                const int* __restrict__ seqlen,
                                float* __restrict__ out_scal)
{
  if (threadIdx.x == 0) {
    double masks = 2.0 * L_ * (double)(seqlen[0] + seqlen[1] + seqlen[2] + seqlen[3]);
    double sel  = acc[0] / masks;
    double spl  = acc[1] / (acc[2] + 1e-7);
    double loss = 0.15 * sel + 0.7 * spl;
    out_scal[0] = (float)acc[4];  // tp
    out_scal[1] = (float)acc[5];  // tn
    out_scal[2] = (float)acc[6];  // fp
    out_scal[3] = (float)loss;    // loss
    out_scal[4] = (float)acc[3];  // accuracysum
    out_scal[5] = (float)acc[2];  // valsum
  }
}

extern "C" void kernel_launch(void* const* d_in, const int* in_sizes, int n_in,
                              void* d_out, int out_size, void* d_ws, size_t ws_size,
                              hipStream_t stream) {
  const float* x      = (const float*)d_in[0];
  const int*   start  = (const int*)  d_in[1];
  const int*   end    = (const int*)  d_in[2];
  const int*   span   = (const int*)  d_in[3];
  const int*   val    = (const int*)  d_in[4];
  const int*   seqlen = (const int*)  d_in[5];
  const float* w_se   = (const float*)d_in[6];
  const float* b_se   = (const float*)d_in[7];
  const float* w_sp   = (const float*)d_in[8];
  const float* b_sp   = (const float*)d_in[9];

  float* out = (float*)d_out;
  const size_t span_elems = (size_t)B_ * L_ * N_ * N_;   // 67,108,864
  const size_t se_elems   = (size_t)B_ * L_ * N_;        // 65,536
  float* out_span  = out;
  float* out_start = out + span_elems;
  float* out_end   = out_start + se_elems;
  float* out_scal  = out_end + se_elems;

  char* ws = (char*)d_ws;
  double* acc     = (double*)ws;                          // 8 doubles (64 B)
  float*  sx_t    = (float*)(ws + 64);                    // 262144 B
  float*  ex_t    = (float*)(ws + 64 + 262144);           // 262144 B
  int*    spi     = (int*)  (ws + 64 + 2 * 262144);       // 262144 B
  int*    epi     = (int*)  (ws + 64 + 3 * 262144);       // 262144 B
  float*  part    = (float*)(ws + 64 + 4 * 262144);       // 8192*8*4 = 256 KiB
  float*  part_se = (float*)(ws + 64 + 4 * 262144 + 262144); // 512*4 B

  (void)hipMemsetAsync(acc, 0, 64, stream);

  head_kernel<<<512, 256, 0, stream>>>(
      x, start, end, seqlen, w_se, b_se, w_sp, b_sp,
      out_start, out_end, sx_t, ex_t, spi, epi, part_se);

  span_kernel<<<8192, 256, 0, stream>>>(
      span, val, sx_t, ex_t, spi, epi, out_span, part);

  reduce_kernel<<<64, 256, 0, stream>>>(part, part_se, acc);

  finalize_kernel<<<1, 64, 0, stream>>>(acc, seqlen, out_scal);
}